// Round 4
// baseline (201.569 us; speedup 1.0000x reference)
//
#include <hip/hip_runtime.h>
#include <cstdint>
#include <cstddef>

// Problem constants (reference: B=8, S=4096, N_STATE=1024, N_HEAD=16)
#define S_LEN   4096
#define NROT    32
#define NGRP    8192    // groups of 64 rows (64x64 fp32 tile each)

typedef __attribute__((ext_vector_type(8))) short  short8x;  // 8 bf16 (4 VGPR)
typedef __attribute__((ext_vector_type(4))) float  floatx4;  // 4 f32

__device__ __host__ inline unsigned short f2bf(float f) {
  union { float f; unsigned u; } c; c.f = f;
  unsigned u = c.u;
  return (unsigned short)((u + 0x7fffu + ((u >> 16) & 1u)) >> 16);
}
__device__ inline float bf2f(unsigned short h) {
  union { unsigned u; float f; } c; c.u = ((unsigned)h) << 16;
  return c.f;
}

// ---------------------------------------------------------------------------
// Setup: blocks 0..511 fill cos/sin tables (4096 x 32 each).
// Block 512: compose M = G0..G31 * R, split into bf16 hi/lo, and emit the
// 16 B-operand MFMA fragments (nt x ks x {hi,lo}) in lane-fragment order:
//   Bfrag[f*64 + lane] = 8 bf16: B[k = ks*32 + (lane>>4)*8 + j][col = nt*16 + (lane&15)]
// ---------------------------------------------------------------------------
__global__ void setup_kernel(const float* __restrict__ thetas,
                             const float* __restrict__ theta_scale,
                             const float* __restrict__ r_matrix,
                             const int*   __restrict__ r_pairs,
                             const float* __restrict__ inv_freq,
                             uint4* __restrict__ Bfrag,
                             float* __restrict__ cosT,
                             float* __restrict__ sinT) {
  if (blockIdx.x < 512) {
    int idx = blockIdx.x * 256 + threadIdx.x;   // 0..131071 = s*32 + f
    int s = idx >> 5;
    int f = idx & 31;
    float ang = (float)s * inv_freq[f];
    cosT[idx] = cosf(ang);
    sinT[idx] = sinf(ang);
    return;
  }
  __shared__ float C[64 * 65];                  // rotations applied to identity
  __shared__ float Mm[64 * 64];                 // final M = C * R (row-major)
  int tid = threadIdx.x;
  if (tid < 64) {
    for (int c = 0; c < 64; ++c) C[tid * 65 + c] = (tid == c) ? 1.0f : 0.0f;
    float sc = theta_scale[0];
    for (int q = 0; q < NROT; ++q) {
      float th = thetas[q] * sc;
      float cs = cosf(th), sn = sinf(th);
      int i = r_pairs[2 * q], j = r_pairs[2 * q + 1];
      float xi = C[tid * 65 + i];
      float xj = C[tid * 65 + j];
      C[tid * 65 + i] =  xi * cs + xj * sn;
      C[tid * 65 + j] = -xi * sn + xj * cs;
    }
  }
  __syncthreads();
  for (int o = tid; o < 64 * 64; o += 256) {
    int t = o >> 6, c = o & 63;
    float a = 0.0f;
    for (int k = 0; k < 64; ++k) a = fmaf(C[t * 65 + k], r_matrix[k * 64 + c], a);
    Mm[o] = a;
  }
  __syncthreads();
  // emit 16 fragments x 64 lanes
  for (int e = tid; e < 16 * 64; e += 256) {
    int f = e >> 6, l = e & 63;
    int hl = f & 1, ks = (f >> 1) & 1, nt = f >> 2;
    int col = nt * 16 + (l & 15);
    unsigned short w[8];
    for (int j = 0; j < 8; ++j) {
      int k = ks * 32 + (l >> 4) * 8 + j;
      float m = Mm[k * 64 + col];
      unsigned short h = f2bf(m);
      if (hl == 0) w[j] = h;
      else         w[j] = f2bf(m - bf2f(h));
    }
    uint4 pk;
    pk.x = (unsigned)w[0] | ((unsigned)w[1] << 16);
    pk.y = (unsigned)w[2] | ((unsigned)w[3] << 16);
    pk.z = (unsigned)w[4] | ((unsigned)w[5] << 16);
    pk.w = (unsigned)w[6] | ((unsigned)w[7] << 16);
    Bfrag[e] = pk;
  }
}

// ---------------------------------------------------------------------------
// Main: ONE wave per 64x64 group (8192 waves, 2048 blocks) so the machine is
// grid-saturated to the VGPR occupancy cap. A-fragments read straight from
// global (8 contiguous fp32/lane), converted to bf16 hi/lo in regs.
// y = A*M via 6 mfma_f32_16x16x32_bf16 per 16x16 tile in TWO independent
// 3-deep chains (ks0/ks1). Epilogue: RoPE pair via shfl_xor(1); NON-TEMPORAL
// dword stores (out is never re-read; keep x L3-resident). No LDS/barriers.
// ---------------------------------------------------------------------------
__global__ __launch_bounds__(256)
void rotary_main(const float* __restrict__ x,
                 const uint4* __restrict__ Bfrag,
                 const float* __restrict__ cosT,
                 const float* __restrict__ sinT,
                 float* __restrict__ out) {
  const int tid  = threadIdx.x;
  const int lane = tid & 63;
  const int wid  = tid >> 6;
  const int g    = blockIdx.x * 4 + wid;        // group id 0..8191

  // B fragments: 16 x 16B per lane (compiler keeps hot / L1-resident)
  const short8x* Bp = (const short8x*)Bfrag;

  const int lr = lane & 15;                     // row-within-tile (A) / col (C)
  const int lk = lane >> 4;                     // k-block (A) / row-block (C)
  const int dq = lr >> 1;                       // pair index within tile cols

  const float* xg = x + (size_t)g * 4096;
  float* og = out + (size_t)g * 4096;

  #pragma unroll
  for (int mt = 0; mt < 4; ++mt) {
    // A: 8 contiguous fp32 per lane per k-step
    const float* xr = xg + (size_t)(mt * 16 + lr) * 64 + lk * 8;
    floatx4 a00 = *(const floatx4*)(xr);
    floatx4 a01 = *(const floatx4*)(xr + 4);
    floatx4 a10 = *(const floatx4*)(xr + 32);
    floatx4 a11 = *(const floatx4*)(xr + 36);

    short8x Ah0, Al0, Ah1, Al1;
    #pragma unroll
    for (int i = 0; i < 8; ++i) {
      float v0 = (i < 4) ? a00[i] : a01[i - 4];
      float v1 = (i < 4) ? a10[i] : a11[i - 4];
      unsigned short h0 = f2bf(v0);
      unsigned short h1 = f2bf(v1);
      Ah0[i] = (short)h0; Al0[i] = (short)f2bf(v0 - bf2f(h0));
      Ah1[i] = (short)h1; Al1[i] = (short)f2bf(v1 - bf2f(h1));
    }

    const int spos = (g * 4 + mt) & (S_LEN - 1);   // wave-uniform seq pos
    const float* ct = cosT + spos * 32;
    const float* st = sinT + spos * 32;

    #pragma unroll
    for (int nt = 0; nt < 4; ++nt) {
      short8x b0 = Bp[(nt * 4 + 0) * 64 + lane];
      short8x b1 = Bp[(nt * 4 + 1) * 64 + lane];
      short8x b2 = Bp[(nt * 4 + 2) * 64 + lane];
      short8x b3 = Bp[(nt * 4 + 3) * 64 + lane];

      floatx4 acc0 = {0.f, 0.f, 0.f, 0.f};
      floatx4 acc1 = {0.f, 0.f, 0.f, 0.f};
      // two independent 3-deep chains (ks0 in acc0, ks1 in acc1)
      acc0 = __builtin_amdgcn_mfma_f32_16x16x32_bf16(Ah0, b0, acc0, 0, 0, 0); // Ah*Bh ks0
      acc1 = __builtin_amdgcn_mfma_f32_16x16x32_bf16(Ah1, b2, acc1, 0, 0, 0); // Ah*Bh ks1
      acc0 = __builtin_amdgcn_mfma_f32_16x16x32_bf16(Ah0, b1, acc0, 0, 0, 0); // Ah*Bl ks0
      acc1 = __builtin_amdgcn_mfma_f32_16x16x32_bf16(Ah1, b3, acc1, 0, 0, 0); // Ah*Bl ks1
      acc0 = __builtin_amdgcn_mfma_f32_16x16x32_bf16(Al0, b0, acc0, 0, 0, 0); // Al*Bh ks0
      acc1 = __builtin_amdgcn_mfma_f32_16x16x32_bf16(Al1, b2, acc1, 0, 0, 0); // Al*Bh ks1

      // epilogue: logical col = nt*16 + lr, pair d = nt*8 + dq
      const float cv = ct[nt * 8 + dq];
      const float sv = st[nt * 8 + dq];
      const int colout = (lane & 1) ? (32 + nt * 8 + dq) : (nt * 8 + dq);
      float* op = og + (size_t)(mt * 16 + lk * 4) * 64 + colout;
      #pragma unroll
      for (int r = 0; r < 4; ++r) {
        float v = acc0[r] + acc1[r];
        float p = __shfl_xor(v, 1, 64);
        float o = (lane & 1) ? fmaf(p, sv, v * cv)      // out[32+d] = x1*s + x2*c
                             : fmaf(v, cv, -(p * sv));  // out[d]    = x1*c - x2*s
        __builtin_nontemporal_store(o, op + r * 64);
      }
    }
  }
}

extern "C" void kernel_launch(void* const* d_in, const int* in_sizes, int n_in,
                              void* d_out, int out_size, void* d_ws, size_t ws_size,
                              hipStream_t stream) {
  const float* x           = (const float*)d_in[0];
  const float* thetas      = (const float*)d_in[1];
  const float* theta_scale = (const float*)d_in[2];
  const float* r_matrix    = (const float*)d_in[3];
  const float* inv_freq    = (const float*)d_in[4];
  const int*   r_pairs     = (const int*)d_in[5];

  uint4* Bfrag = (uint4*)d_ws;                  // 16*64*16B = 16KB
  float* cosT  = (float*)d_ws + 4096;           // 512KB
  float* sinT  = cosT + S_LEN * 32;             // 512KB
  float* outp  = (float*)d_out;

  setup_kernel<<<513, 256, 0, stream>>>(thetas, theta_scale, r_matrix, r_pairs,
                                        inv_freq, Bfrag, cosT, sinT);
  rotary_main<<<NGRP / 4, 256, 0, stream>>>(x, Bfrag, cosT, sinT, outp);
}

// Round 5
// 82.234 us; speedup vs baseline: 2.4511x; 2.4511x over previous
//
#include <hip/hip_runtime.h>
#include <cstdint>
#include <cstddef>

// Problem constants (reference: B=8, S=4096, N_STATE=1024, N_HEAD=16)
#define S_LEN   4096
#define NROT    32
#define NGRP    8192    // groups of 64 rows (64x64 fp32 tile each)

typedef __attribute__((ext_vector_type(8))) short  short8x;  // 8 bf16 (4 VGPR)
typedef __attribute__((ext_vector_type(4))) float  floatx4;  // 4 f32

__device__ __host__ inline unsigned short f2bf(float f) {
  union { float f; unsigned u; } c; c.f = f;
  unsigned u = c.u;
  return (unsigned short)((u + 0x7fffu + ((u >> 16) & 1u)) >> 16);
}
__device__ inline float bf2f(unsigned short h) {
  union { unsigned u; float f; } c; c.u = ((unsigned)h) << 16;
  return c.f;
}

// ---------------------------------------------------------------------------
// Setup: blocks 0..511 fill cos/sin tables (4096 x 32 each).
// Block 512: compose M = G0..G31 * R, split into bf16 hi/lo, and emit the
// 16 B-operand MFMA fragments (nt x ks x {hi,lo}) in lane-fragment order:
//   Bfrag[f*64 + lane] = 8 bf16: B[k = ks*32 + (lane>>4)*8 + j][col = nt*16 + (lane&15)]
// ---------------------------------------------------------------------------
__global__ void setup_kernel(const float* __restrict__ thetas,
                             const float* __restrict__ theta_scale,
                             const float* __restrict__ r_matrix,
                             const int*   __restrict__ r_pairs,
                             const float* __restrict__ inv_freq,
                             uint4* __restrict__ Bfrag,
                             float* __restrict__ cosT,
                             float* __restrict__ sinT) {
  if (blockIdx.x < 512) {
    int idx = blockIdx.x * 256 + threadIdx.x;   // 0..131071 = s*32 + f
    int s = idx >> 5;
    int f = idx & 31;
    float ang = (float)s * inv_freq[f];
    cosT[idx] = cosf(ang);
    sinT[idx] = sinf(ang);
    return;
  }
  __shared__ float C[64 * 65];                  // rotations applied to identity
  __shared__ float Mm[64 * 64];                 // final M = C * R (row-major)
  int tid = threadIdx.x;
  if (tid < 64) {
    for (int c = 0; c < 64; ++c) C[tid * 65 + c] = (tid == c) ? 1.0f : 0.0f;
    float sc = theta_scale[0];
    for (int q = 0; q < NROT; ++q) {
      float th = thetas[q] * sc;
      float cs = cosf(th), sn = sinf(th);
      int i = r_pairs[2 * q], j = r_pairs[2 * q + 1];
      float xi = C[tid * 65 + i];
      float xj = C[tid * 65 + j];
      C[tid * 65 + i] =  xi * cs + xj * sn;
      C[tid * 65 + j] = -xi * sn + xj * cs;
    }
  }
  __syncthreads();
  for (int o = tid; o < 64 * 64; o += 256) {
    int t = o >> 6, c = o & 63;
    float a = 0.0f;
    for (int k = 0; k < 64; ++k) a = fmaf(C[t * 65 + k], r_matrix[k * 64 + c], a);
    Mm[o] = a;
  }
  __syncthreads();
  // emit 16 fragments x 64 lanes
  for (int e = tid; e < 16 * 64; e += 256) {
    int f = e >> 6, l = e & 63;
    int hl = f & 1, ks = (f >> 1) & 1, nt = f >> 2;
    int col = nt * 16 + (l & 15);
    unsigned short w[8];
    for (int j = 0; j < 8; ++j) {
      int k = ks * 32 + (l >> 4) * 8 + j;
      float m = Mm[k * 64 + col];
      unsigned short h = f2bf(m);
      if (hl == 0) w[j] = h;
      else         w[j] = f2bf(m - bf2f(h));
    }
    uint4 pk;
    pk.x = (unsigned)w[0] | ((unsigned)w[1] << 16);
    pk.y = (unsigned)w[2] | ((unsigned)w[3] << 16);
    pk.z = (unsigned)w[4] | ((unsigned)w[5] << 16);
    pk.w = (unsigned)w[6] | ((unsigned)w[7] << 16);
    Bfrag[e] = pk;
  }
}

// ---------------------------------------------------------------------------
// Main: one wave per 64x64 group (8192 waves, 2048 blocks). A loaded straight
// from global with mt+1 prefetched under mt's compute. y = A*M via dual
// 3-deep mfma_f32_16x16x32_bf16 chains (split-bf16). Epilogue: RoPE pair via
// shfl_xor(1), then a wave-private 4KB LDS transpose (XOR-swizzled, bank-
// clean) so the global stores are 4x dwordx4 fully-coalesced 1KB runs per
// tile. Plain (cached) stores — NT regressed 2x in R4. No cross-wave sync.
// ---------------------------------------------------------------------------
__global__ __launch_bounds__(256)
void rotary_main(const float* __restrict__ x,
                 const uint4* __restrict__ Bfrag,
                 const float* __restrict__ cosT,
                 const float* __restrict__ sinT,
                 float* __restrict__ out) {
  __shared__ float obuf[4][1024];               // 4 waves x 4KB transpose buf
  const int tid  = threadIdx.x;
  const int lane = tid & 63;
  const int wid  = tid >> 6;
  const int g    = blockIdx.x * 4 + wid;        // group id 0..8191

  const short8x* Bp = (const short8x*)Bfrag;

  const int lr  = lane & 15;                    // A row-in-tile / C col-in-tile
  const int lk  = lane >> 4;                    // A k-block / C row-block
  const int dq  = lr >> 1;                      // pair index within tile cols
  const int par = lane & 1;

  const float* xg = x + (size_t)g * 4096;
  float* og = out + (size_t)g * 4096;
  float* ob = &obuf[wid][0];

  floatx4 a[2][4];
  // load A fragments for tile mt into a[sl]
  #define LOAD_A(mt, sl)                                                  \
    { const float* xr = xg + (size_t)((mt) * 16 + lr) * 64 + lk * 8;      \
      a[sl][0] = *(const floatx4*)(xr);                                   \
      a[sl][1] = *(const floatx4*)(xr + 4);                               \
      a[sl][2] = *(const floatx4*)(xr + 32);                              \
      a[sl][3] = *(const floatx4*)(xr + 36); }

  LOAD_A(0, 0)

  #pragma unroll
  for (int mt = 0; mt < 4; ++mt) {
    const int cur = mt & 1;
    // convert current A to bf16 hi/lo
    short8x Ah0, Al0, Ah1, Al1;
    #pragma unroll
    for (int i = 0; i < 8; ++i) {
      float v0 = (i < 4) ? a[cur][0][i] : a[cur][1][i - 4];
      float v1 = (i < 4) ? a[cur][2][i] : a[cur][3][i - 4];
      unsigned short h0 = f2bf(v0);
      unsigned short h1 = f2bf(v1);
      Ah0[i] = (short)h0; Al0[i] = (short)f2bf(v0 - bf2f(h0));
      Ah1[i] = (short)h1; Al1[i] = (short)f2bf(v1 - bf2f(h1));
    }
    // prefetch next tile's A under this tile's compute
    if (mt < 3) LOAD_A(mt + 1, (mt + 1) & 1)

    const int spos = (g * 4 + mt) & (S_LEN - 1);   // wave-uniform seq pos
    const float* ct = cosT + spos * 32;
    const float* st = sinT + spos * 32;

    #pragma unroll
    for (int nt = 0; nt < 4; ++nt) {
      short8x b0 = Bp[(nt * 4 + 0) * 64 + lane];
      short8x b1 = Bp[(nt * 4 + 1) * 64 + lane];
      short8x b2 = Bp[(nt * 4 + 2) * 64 + lane];
      short8x b3 = Bp[(nt * 4 + 3) * 64 + lane];

      floatx4 acc0 = {0.f, 0.f, 0.f, 0.f};
      floatx4 acc1 = {0.f, 0.f, 0.f, 0.f};
      acc0 = __builtin_amdgcn_mfma_f32_16x16x32_bf16(Ah0, b0, acc0, 0, 0, 0); // Ah*Bh ks0
      acc1 = __builtin_amdgcn_mfma_f32_16x16x32_bf16(Ah1, b2, acc1, 0, 0, 0); // Ah*Bh ks1
      acc0 = __builtin_amdgcn_mfma_f32_16x16x32_bf16(Ah0, b1, acc0, 0, 0, 0); // Ah*Bl ks0
      acc1 = __builtin_amdgcn_mfma_f32_16x16x32_bf16(Ah1, b3, acc1, 0, 0, 0); // Ah*Bl ks1
      acc0 = __builtin_amdgcn_mfma_f32_16x16x32_bf16(Al0, b0, acc0, 0, 0, 0); // Al*Bh ks0
      acc1 = __builtin_amdgcn_mfma_f32_16x16x32_bf16(Al1, b2, acc1, 0, 0, 0); // Al*Bh ks1

      // RoPE: y cols (2d,2d+1) -> out cols d / 32+d, d = nt*8+dq
      const float cv = ct[nt * 8 + dq];
      const float sv = st[nt * 8 + dq];
      const int colout = par ? (32 + nt * 8 + dq) : (nt * 8 + dq);
      #pragma unroll
      for (int r = 0; r < 4; ++r) {
        float v = acc0[r] + acc1[r];
        float p = __shfl_xor(v, 1, 64);
        float o = par ? fmaf(p, sv, v * cv)      // out[32+d] = y1*s + y2*c
                      : fmaf(v, cv, -(p * sv));  // out[d]    = y1*c - y2*s
        // swizzled LDS write: word = row_local*64 + (col ^ (lk<<3))
        ob[(lk * 4 + r) * 64 + (colout ^ (lk << 3))] = o;
      }
    }

    // drain LDS writes, then read back coalesced and store 4x 1KB runs
    asm volatile("s_waitcnt lgkmcnt(0)" ::: "memory");
    #pragma unroll
    for (int q = 0; q < 4; ++q) {
      const float* rp = ob + q * 256 + lk * 64 + ((lr * 4) ^ (q << 3));
      floatx4 vr = *(const floatx4*)rp;
      *(floatx4*)(og + (size_t)(mt * 16 + q * 4 + lk) * 64 + lr * 4) = vr;
    }
  }
  #undef LOAD_A
}

extern "C" void kernel_launch(void* const* d_in, const int* in_sizes, int n_in,
                              void* d_out, int out_size, void* d_ws, size_t ws_size,
                              hipStream_t stream) {
  const float* x           = (const float*)d_in[0];
  const float* thetas      = (const float*)d_in[1];
  const float* theta_scale = (const float*)d_in[2];
  const float* r_matrix    = (const float*)d_in[3];
  const float* inv_freq    = (const float*)d_in[4];
  const int*   r_pairs     = (const int*)d_in[5];

  uint4* Bfrag = (uint4*)d_ws;                  // 16*64*16B = 16KB
  float* cosT  = (float*)d_ws + 4096;           // 512KB
  float* sinT  = cosT + S_LEN * 32;             // 512KB
  float* outp  = (float*)d_out;

  setup_kernel<<<513, 256, 0, stream>>>(thetas, theta_scale, r_matrix, r_pairs,
                                        inv_freq, Bfrag, cosT, sinT);
  rotary_main<<<NGRP / 4, 256, 0, stream>>>(x, Bfrag, cosT, sinT, outp);
}